// Round 1
// baseline (255.505 us; speedup 1.0000x reference)
//
#include <hip/hip_runtime.h>

// PositionalSparseLinear2d: out[b,o] = sum_k input[b, conn[o,k]] * weights[o,k]
// B=64, N_in = N_out = 512*512 = 262144, K=8, all fp32.

#define IN_N  (512*512)
#define OUT_N (512*512)
#define BATCH 64
#define KCONN 8

// ---------------------------------------------------------------------------
// Kernel 1: transpose input (BATCH, IN_N) -> x_t (IN_N, BATCH) so the batch
// dimension is contiguous (one idx-row = 64 floats = 256 B = 4 full cache
// lines). Classic LDS-tiled transpose, 64x64 tile, float4 on both sides.
// ---------------------------------------------------------------------------
__global__ __launch_bounds__(256) void transpose_kernel(const float* __restrict__ in,
                                                        float* __restrict__ xt) {
    __shared__ float lds[64][65];   // +1 pad: column reads conflict-free
    const int t    = threadIdx.x;
    const int idx0 = blockIdx.x * 64;
    const int tr   = t >> 4;         // 0..15
    const int tc   = (t & 15) << 2;  // 0,4,...,60

#pragma unroll
    for (int p = 0; p < 4; ++p) {
        const int b = tr + p * 16;   // batch row
        float4 v = *(const float4*)(in + (size_t)b * IN_N + idx0 + tc);
        lds[b][tc + 0] = v.x;
        lds[b][tc + 1] = v.y;
        lds[b][tc + 2] = v.z;
        lds[b][tc + 3] = v.w;
    }
    __syncthreads();
#pragma unroll
    for (int p = 0; p < 4; ++p) {
        const int ii = tr + p * 16;  // idx within tile
        float4 u;
        u.x = lds[tc + 0][ii];
        u.y = lds[tc + 1][ii];
        u.z = lds[tc + 2][ii];
        u.w = lds[tc + 3][ii];
        *(float4*)(xt + (size_t)(idx0 + ii) * BATCH + tc) = u;
    }
}

// ---------------------------------------------------------------------------
// Kernel 2: gather + weighted sum on the transposed layout.
// Thread owns one output position o and HALF the batches (32): per connection
// k it streams the 128 B half-row as 8 float4 loads (fully-consumed cache
// lines) and FMAs into 32 accumulators. blockIdx.y in {0,1} picks the half;
// the two halves touch disjoint lines of each 256 B row.
// ---------------------------------------------------------------------------
__global__ __launch_bounds__(256) void gather_kernel(const float* __restrict__ xt,
                                                     const int* __restrict__ conn,
                                                     const float* __restrict__ w,
                                                     float* __restrict__ out) {
    const int o = blockIdx.x * 256 + threadIdx.x;
    const int h = blockIdx.y * 32;   // batch half offset (0 or 32)

    const int4   c0 = ((const int4*)conn)[(size_t)o * 2 + 0];
    const int4   c1 = ((const int4*)conn)[(size_t)o * 2 + 1];
    const float4 w0 = ((const float4*)w)[(size_t)o * 2 + 0];
    const float4 w1 = ((const float4*)w)[(size_t)o * 2 + 1];

    const int   cidx[KCONN] = {c0.x, c0.y, c0.z, c0.w, c1.x, c1.y, c1.z, c1.w};
    const float wk[KCONN]   = {w0.x, w0.y, w0.z, w0.w, w1.x, w1.y, w1.z, w1.w};

    float acc[32];
#pragma unroll
    for (int b = 0; b < 32; ++b) acc[b] = 0.0f;

#pragma unroll
    for (int k = 0; k < KCONN; ++k) {
        const float4* row = (const float4*)(xt + (size_t)cidx[k] * BATCH + h);
        const float wv = wk[k];
#pragma unroll
        for (int q = 0; q < 8; ++q) {
            float4 v = row[q];
            acc[q * 4 + 0] += v.x * wv;
            acc[q * 4 + 1] += v.y * wv;
            acc[q * 4 + 2] += v.z * wv;
            acc[q * 4 + 3] += v.w * wv;
        }
    }

#pragma unroll
    for (int b = 0; b < 32; ++b) {
        out[(size_t)(h + b) * OUT_N + o] = acc[b];   // coalesced across o
    }
}

// ---------------------------------------------------------------------------
// Fallback (only if workspace is too small for the 64 MiB transposed copy):
// direct gather on the original layout. Correct but cache-line-wasteful.
// ---------------------------------------------------------------------------
__global__ __launch_bounds__(256) void direct_kernel(const float* __restrict__ in,
                                                     const int* __restrict__ conn,
                                                     const float* __restrict__ w,
                                                     float* __restrict__ out) {
    const int o = blockIdx.x * 256 + threadIdx.x;

    const int4   c0 = ((const int4*)conn)[(size_t)o * 2 + 0];
    const int4   c1 = ((const int4*)conn)[(size_t)o * 2 + 1];
    const float4 w0 = ((const float4*)w)[(size_t)o * 2 + 0];
    const float4 w1 = ((const float4*)w)[(size_t)o * 2 + 1];

    const int   cidx[KCONN] = {c0.x, c0.y, c0.z, c0.w, c1.x, c1.y, c1.z, c1.w};
    const float wk[KCONN]   = {w0.x, w0.y, w0.z, w0.w, w1.x, w1.y, w1.z, w1.w};

    for (int b = 0; b < BATCH; ++b) {
        const float* xb = in + (size_t)b * IN_N;
        float acc = 0.0f;
#pragma unroll
        for (int k = 0; k < KCONN; ++k) acc += xb[cidx[k]] * wk[k];
        out[(size_t)b * OUT_N + o] = acc;
    }
}

extern "C" void kernel_launch(void* const* d_in, const int* in_sizes, int n_in,
                              void* d_out, int out_size, void* d_ws, size_t ws_size,
                              hipStream_t stream) {
    const float* inp  = (const float*)d_in[0];   // (64, 512, 512) fp32
    const int*   conn = (const int*)d_in[1];     // (262144, 8) int32
    const float* w    = (const float*)d_in[2];   // (262144, 8) fp32
    float*       out  = (float*)d_out;           // (64, 262144) fp32

    const size_t xt_bytes = (size_t)IN_N * BATCH * sizeof(float);  // 64 MiB

    if (ws_size >= xt_bytes) {
        float* xt = (float*)d_ws;
        transpose_kernel<<<IN_N / 64, 256, 0, stream>>>(inp, xt);
        dim3 grid(OUT_N / 256, 2);
        gather_kernel<<<grid, 256, 0, stream>>>(xt, conn, w, out);
    } else {
        direct_kernel<<<OUT_N / 256, 256, 0, stream>>>(inp, conn, w, out);
    }
}